// Round 2
// baseline (531.896 us; speedup 1.0000x reference)
//
#include <hip/hip_runtime.h>
#include <stdint.h>

static constexpr int BLOCK = 256;
static constexpr int ITEMS = 8;
static constexpr int CHUNK = BLOCK * ITEMS;   // 2048 elements per block
static constexpr int MAXNB = 1024;            // 1024 * 2048 = 2097152 = N

#define GAMMA_F 0.99f
static __device__ __forceinline__ float gl_const() { return (float)(0.99 * 0.95); }

// affine compose: self ∘ right (right applied first): x -> a1*(a2*x+b2)+b1
__device__ __forceinline__ void compose(float& a1, float& b1, float a2, float b2) {
    b1 = fmaf(a1, b2, b1);
    a1 = a1 * a2;
}

// ---------------- bool dtype runtime probe ----------------
// 0 = int32, 1 = uint8/bool, 2 = float32. Byte pattern of first 1024 bytes.
__device__ __forceinline__ int detect_mode(const void* term, int n_elems, int* flg) {
    int t = threadIdx.x;
    if (t == 0) { flg[0] = 0; flg[1] = 0; }
    __syncthreads();
    if (t < 256) {
        const unsigned char* p = (const unsigned char*)term;
        int i0 = 4 * t;
        if (i0 + 3 < n_elems) {
            unsigned b1 = p[i0 + 1], b2 = p[i0 + 2], b3 = p[i0 + 3];
            if (b1) atomicOr(&flg[0], 1);
            if (b2 | b3) atomicOr(&flg[1], 1);
        }
    }
    __syncthreads();
    return flg[0] ? 1 : (flg[1] ? 2 : 0);
}

__device__ __forceinline__ int load_bool1(const void* p, long i, int mode) {
    if (mode == 1) return ((const unsigned char*)p)[i] != 0;
    if (mode == 0) return ((const int*)p)[i] != 0;
    return ((const float*)p)[i] != 0.0f;
}

__device__ __forceinline__ void load_bool8(const void* p, long base, int mode, int* f) {
    if (mode == 1) {
        uint2 q = *(const uint2*)((const unsigned char*)p + base);
        unsigned w[2] = {q.x, q.y};
#pragma unroll
        for (int j = 0; j < 8; ++j) f[j] = (int)((w[j >> 2] >> ((j & 3) * 8)) & 0xffu);
    } else if (mode == 0) {
        const int4* q = (const int4*)((const int*)p + base);
#pragma unroll
        for (int k = 0; k < 2; ++k) {
            int4 v = q[k];
            f[4*k] = v.x; f[4*k+1] = v.y; f[4*k+2] = v.z; f[4*k+3] = v.w;
        }
    } else {
        const float4* q = (const float4*)((const float*)p + base);
#pragma unroll
        for (int k = 0; k < 2; ++k) {
            float4 v = q[k];
            f[4*k] = v.x != 0.f; f[4*k+1] = v.y != 0.f; f[4*k+2] = v.z != 0.f; f[4*k+3] = v.w != 0.f;
        }
    }
}

// c[j] = not_done * gamma*lambda ; d[j] = r + gamma*not_term*nv - v
__device__ __forceinline__ void compute_cd(
    const float* __restrict__ rewards, const float* __restrict__ values,
    const float* __restrict__ next_values, const void* __restrict__ term,
    const void* __restrict__ trunc, int mode, long base, int n,
    float* c, float* d, float* v)
{
    const float GL = gl_const();
    if (base + ITEMS <= n) {
        float r[ITEMS], nv[ITEMS];
        const float4* r4 = (const float4*)(rewards + base);
        const float4* v4 = (const float4*)(values + base);
        const float4* n4 = (const float4*)(next_values + base);
#pragma unroll
        for (int k = 0; k < 2; ++k) {
            float4 a = r4[k]; r[4*k]=a.x; r[4*k+1]=a.y; r[4*k+2]=a.z; r[4*k+3]=a.w;
            float4 b = v4[k]; v[4*k]=b.x; v[4*k+1]=b.y; v[4*k+2]=b.z; v[4*k+3]=b.w;
            float4 q = n4[k]; nv[4*k]=q.x; nv[4*k+1]=q.y; nv[4*k+2]=q.z; nv[4*k+3]=q.w;
        }
        int tm[ITEMS], tr[ITEMS];
        load_bool8(term,  base, mode, tm);
        load_bool8(trunc, base, mode, tr);
#pragma unroll
        for (int j = 0; j < ITEMS; ++j) {
            float nt = tm[j] ? 0.f : 1.f;
            float nd = (tm[j] | tr[j]) ? 0.f : 1.f;
            d[j] = r[j] + GAMMA_F * nt * nv[j] - v[j];
            c[j] = nd * GL;
        }
    } else {
#pragma unroll
        for (int j = 0; j < ITEMS; ++j) {
            long i = base + j;
            if (i < (long)n) {
                int tm = load_bool1(term, i, mode);
                int tr = load_bool1(trunc, i, mode);
                float nt = tm ? 0.f : 1.f;
                float nd = (tm | tr) ? 0.f : 1.f;
                v[j] = values[i];
                d[j] = rewards[i] + GAMMA_F * nt * next_values[i] - v[j];
                c[j] = nd * GL;
            } else { c[j] = 1.f; d[j] = 0.f; v[j] = 0.f; }
        }
    }
}

// ================= FUSED kernel with DISTRIBUTED flag barrier =================
// grid.sync() was 1024 serialized same-address device atomics (~200 µs on
// MI355X — round-5 lesson). Replaced with: per-block release-store to a
// DISTINCT flag + all-blocks acquire-poll of the 1024 flags (4 KB, L2
// broadcast, no RMW serialization). Flags are memset to 0 on the stream
// before launch. Cooperative launch retained only for the co-residency
// guarantee (1024 blocks = 4/CU exactly at __launch_bounds__(256,4)).
__global__ __launch_bounds__(BLOCK, 4) void k_fused(
    const float* __restrict__ rewards, const float* __restrict__ values,
    const float* __restrict__ next_values, const float* __restrict__ lp,
    const float* __restrict__ olp, const void* __restrict__ term,
    const void* __restrict__ trunc, float2* __restrict__ blockAgg,
    float4* __restrict__ bs4, float* __restrict__ bs1, int* __restrict__ flags,
    float* __restrict__ out, int n, int nb)
{
    __shared__ int flg[2];
    __shared__ float wA[4], wB[4];
    __shared__ float red[4][5];
    __shared__ float sA[BLOCK], sB[BLOCK];
    __shared__ float sS[MAXNB];
    __shared__ double dS[BLOCK], dS2[BLOCK];
    __shared__ float statMean, statInv;

    const int t = threadIdx.x;
    const int lane = t & 63, w = t >> 6;
    const int bid = blockIdx.x;
    const int mode = detect_mode(term, n, flg);
    const long base = (long)bid * CHUNK + (long)t * ITEMS;

    float c[ITEMS], d[ITEMS], v[ITEMS];
    compute_cd(rewards, values, next_values, term, trunc, mode, base, n, c, d, v);

    // ---- phase 1: thread-serial affine aggregate of this thread's 8 items ----
    float a = 1.f, b = 0.f;
#pragma unroll
    for (int j = ITEMS - 1; j >= 0; --j) { b = fmaf(c[j], b, d[j]); a *= c[j]; }

    // wave suffix-inclusive scan via shuffles: H_l = F_l ∘ ... ∘ F_63
#pragma unroll
    for (int dd = 1; dd < 64; dd <<= 1) {
        float ra = __shfl_down(a, dd, 64);
        float rb = __shfl_down(b, dd, 64);
        if (lane + dd < 64) { b = fmaf(a, rb, b); a *= ra; }
    }
    if (lane == 0) { wA[w] = a; wB[w] = b; }   // wave aggregate
    // within-wave exclusive entry E = H_{l+1} (identity at lane 63)
    float ea = __shfl_down(a, 1, 64);
    float eb = __shfl_down(b, 1, 64);
    if (lane == 63) { ea = 1.f; eb = 0.f; }
    __syncthreads();
    // compose with later-wave aggregates (ea,eb stays in registers — no E2)
    for (int ww = w + 1; ww < 4; ++ww) compose(ea, eb, wA[ww], wB[ww]);
    if (t == 0) {
        float Aa = wA[0], Ab = wB[0];
        for (int ww = 1; ww < 4; ++ww) compose(Aa, Ab, wA[ww], wB[ww]);
        blockAgg[bid] = make_float2(Aa, Ab);
    }

    // symbolic replay: adv_j = p*x_b + q ; accumulate 5 moment scalars
    {
        float p = ea, q = eb;
        float sP = 0.f, sQ = 0.f, sP2 = 0.f, sPQ = 0.f, sQ2 = 0.f;
#pragma unroll
        for (int j = ITEMS - 1; j >= 0; --j) {
            p = c[j] * p;
            q = fmaf(c[j], q, d[j]);
            if (base + j < (long)n) {
                sP += p; sQ += q; sP2 += p*p; sPQ += p*q; sQ2 += q*q;
            }
        }
#pragma unroll
        for (int dd = 32; dd > 0; dd >>= 1) {
            sP  += __shfl_down(sP,  dd, 64);
            sQ  += __shfl_down(sQ,  dd, 64);
            sP2 += __shfl_down(sP2, dd, 64);
            sPQ += __shfl_down(sPQ, dd, 64);
            sQ2 += __shfl_down(sQ2, dd, 64);
        }
        if (lane == 0) { red[w][0]=sP; red[w][1]=sQ; red[w][2]=sP2; red[w][3]=sPQ; red[w][4]=sQ2; }
        __syncthreads();
        if (t == 0) {
            float m0=0,m1=0,m2=0,m3=0,m4=0;
            for (int ww = 0; ww < 4; ++ww) { m0+=red[ww][0]; m1+=red[ww][1]; m2+=red[ww][2]; m3+=red[ww][3]; m4+=red[ww][4]; }
            bs4[bid] = make_float4(m0, m1, m2, m3);
            bs1[bid] = m4;
        }
    }

    // prefetch lp/olp into registers — latency hides under the barrier poll
    const bool full = (base + ITEMS <= n);
    float l[ITEMS], o[ITEMS];
    if (full) {
        const float4* l4 = (const float4*)(lp + base);
        const float4* o4 = (const float4*)(olp + base);
#pragma unroll
        for (int k = 0; k < 2; ++k) {
            float4 q = l4[k]; l[4*k]=q.x; l[4*k+1]=q.y; l[4*k+2]=q.z; l[4*k+3]=q.w;
            float4 ww = o4[k]; o[4*k]=ww.x; o[4*k+1]=ww.y; o[4*k+2]=ww.z; o[4*k+3]=ww.w;
        }
    }

    // ---- distributed grid barrier: distinct-address flags, no RMW ----
    // publish: all this block's global writes (blockAgg/bs4/bs1 by t==0) are
    // ordered before the release store of its flag.
    __threadfence();
    if (t == 0)
        __hip_atomic_store(&flags[bid], 1, __ATOMIC_RELEASE, __HIP_MEMORY_SCOPE_AGENT);
    // wait: thread t polls flags[4t..4t+3]; acquire loads bypass stale caches
#pragma unroll
    for (int j = 0; j < 4; ++j) {
        int i = 4 * t + j;
        if (i < nb) {
            while (__hip_atomic_load(&flags[i], __ATOMIC_ACQUIRE, __HIP_MEMORY_SCOPE_AGENT) == 0) {
                __builtin_amdgcn_s_sleep(2);
            }
        }
    }
    __threadfence();     // acquire side: invalidate stale L1/L2 lines before reading blockAgg
    __syncthreads();

    // ---- phase 2: redundant per-block suffix scan of nb aggregates + stats ----
    float la[4], lb[4];
#pragma unroll
    for (int j = 0; j < 4; ++j) {
        int i = 4 * t + j;
        if (i < nb) { float2 f = blockAgg[i]; la[j] = f.x; lb[j] = f.y; }
        else        { la[j] = 1.f; lb[j] = 0.f; }
    }
    a = 1.f; b = 0.f;
#pragma unroll
    for (int j = 3; j >= 0; --j) { b = fmaf(la[j], b, lb[j]); a *= la[j]; }
    sA[t] = a; sB[t] = b;
    __syncthreads();
    for (int dd = 1; dd < BLOCK; dd <<= 1) {
        float ra = 1.f, rb = 0.f;
        if (t + dd < BLOCK) { ra = sA[t + dd]; rb = sB[t + dd]; }
        __syncthreads();
        b = fmaf(a, rb, b);
        a *= ra;
        sA[t] = a; sB[t] = b;
        __syncthreads();
    }
    {
        float x = (t + 1 < BLOCK) ? sB[t + 1] : 0.f;   // suffix entering block 4t+3
        double ds = 0.0, ds2 = 0.0;
#pragma unroll
        for (int j = 3; j >= 0; --j) {
            int i = 4 * t + j;
            if (i < nb) {
                sS[i] = x;
                float4 s4 = bs4[i];
                double xd = (double)x;
                ds  += (double)s4.x * xd + (double)s4.y;
                ds2 += (double)s4.z * xd * xd + 2.0 * (double)s4.w * xd + (double)bs1[i];
            }
            x = fmaf(la[j], x, lb[j]);
        }
        dS[t] = ds; dS2[t] = ds2;
    }
    __syncthreads();
    for (int dd = BLOCK / 2; dd > 0; dd >>= 1) {
        if (t < dd) { dS[t] += dS[t + dd]; dS2[t] += dS2[t + dd]; }
        __syncthreads();
    }
    if (t == 0) {
        double sum = dS[0], sumsq = dS2[0];
        double mean = sum / (double)n;
        double var = (sumsq - sum * sum / (double)n) / (double)(n - 1);
        if (var < 0.0) var = 0.0;
        statMean = (float)mean;
        statInv  = 1.0f / ((float)sqrt(var) + 1e-9f);
    }
    __syncthreads();

    // ---- phase 3: replay + finalize (c,d,v,ea,eb still in registers) ----
    float xx = fmaf(ea, sS[bid], eb);
    float adv[ITEMS];
#pragma unroll
    for (int j = ITEMS - 1; j >= 0; --j) {
        xx = fmaf(c[j], xx, d[j]);
        adv[j] = xx;
    }
    const float mean = statMean;
    const float inv  = statInv;
    if (full) {
        float buf[3 * ITEMS];
#pragma unroll
        for (int j = 0; j < ITEMS; ++j) {
            float an = (adv[j] - mean) * inv;
            float ratio = expf(l[j] - o[j]);
            float cl = fminf(fmaxf(ratio, 0.8f), 1.2f);
            buf[3*j]     = an;
            buf[3*j + 1] = adv[j] + v[j];
            buf[3*j + 2] = -fminf(ratio * an, cl * an);
        }
        float4* dst = (float4*)(out + 3 * base);   // 3*base % 4 == 0 → 16B aligned
#pragma unroll
        for (int k = 0; k < 6; ++k)
            dst[k] = make_float4(buf[4*k], buf[4*k+1], buf[4*k+2], buf[4*k+3]);
    } else {
        for (int j = 0; j < ITEMS; ++j) {
            long i = base + j;
            if (i < (long)n) {
                float an = (adv[j] - mean) * inv;
                float ratio = expf(lp[i] - olp[i]);
                float cl = fminf(fmaxf(ratio, 0.8f), 1.2f);
                out[3*i]     = an;
                out[3*i + 1] = adv[j] + v[j];
                out[3*i + 2] = -fminf(ratio * an, cl * an);
            }
        }
    }
}

// ================= fallback 2-kernel path (proven; used only if coop fails) ==
__global__ __launch_bounds__(BLOCK) void k1_agg(
    const float* __restrict__ rewards, const float* __restrict__ values,
    const float* __restrict__ next_values, const void* __restrict__ term,
    const void* __restrict__ trunc, float2* __restrict__ blockAgg,
    float2* __restrict__ E2, float4* __restrict__ bs4, float* __restrict__ bs1,
    int n)
{
    __shared__ int flg[2];
    __shared__ float wA[4], wB[4];
    __shared__ float red[4][5];

    const int t = threadIdx.x;
    const int lane = t & 63, w = t >> 6;
    const int bid = blockIdx.x;
    const int mode = detect_mode(term, n, flg);
    const long base = (long)bid * CHUNK + (long)t * ITEMS;

    float c[ITEMS], d[ITEMS], v[ITEMS];
    compute_cd(rewards, values, next_values, term, trunc, mode, base, n, c, d, v);

    float a = 1.f, b = 0.f;
#pragma unroll
    for (int j = ITEMS - 1; j >= 0; --j) { b = fmaf(c[j], b, d[j]); a *= c[j]; }

#pragma unroll
    for (int dd = 1; dd < 64; dd <<= 1) {
        float ra = __shfl_down(a, dd, 64);
        float rb = __shfl_down(b, dd, 64);
        if (lane + dd < 64) { b = fmaf(a, rb, b); a *= ra; }
    }
    if (lane == 0) { wA[w] = a; wB[w] = b; }
    float ea = __shfl_down(a, 1, 64);
    float eb = __shfl_down(b, 1, 64);
    if (lane == 63) { ea = 1.f; eb = 0.f; }
    __syncthreads();
    for (int ww = w + 1; ww < 4; ++ww) compose(ea, eb, wA[ww], wB[ww]);
    if (t == 0) {
        float Aa = wA[0], Ab = wB[0];
        for (int ww = 1; ww < 4; ++ww) compose(Aa, Ab, wA[ww], wB[ww]);
        blockAgg[bid] = make_float2(Aa, Ab);
    }
    E2[(long)bid * BLOCK + t] = make_float2(ea, eb);

    float p = ea, q = eb;
    float sP = 0.f, sQ = 0.f, sP2 = 0.f, sPQ = 0.f, sQ2 = 0.f;
#pragma unroll
    for (int j = ITEMS - 1; j >= 0; --j) {
        p = c[j] * p;
        q = fmaf(c[j], q, d[j]);
        if (base + j < (long)n) {
            sP += p; sQ += q; sP2 += p*p; sPQ += p*q; sQ2 += q*q;
        }
    }
#pragma unroll
    for (int dd = 32; dd > 0; dd >>= 1) {
        sP  += __shfl_down(sP,  dd, 64);
        sQ  += __shfl_down(sQ,  dd, 64);
        sP2 += __shfl_down(sP2, dd, 64);
        sPQ += __shfl_down(sPQ, dd, 64);
        sQ2 += __shfl_down(sQ2, dd, 64);
    }
    if (lane == 0) { red[w][0]=sP; red[w][1]=sQ; red[w][2]=sP2; red[w][3]=sPQ; red[w][4]=sQ2; }
    __syncthreads();
    if (t == 0) {
        float m0=0,m1=0,m2=0,m3=0,m4=0;
        for (int ww = 0; ww < 4; ++ww) { m0+=red[ww][0]; m1+=red[ww][1]; m2+=red[ww][2]; m3+=red[ww][3]; m4+=red[ww][4]; }
        bs4[bid] = make_float4(m0, m1, m2, m3);
        bs1[bid] = m4;
    }
}

__global__ __launch_bounds__(BLOCK) void k3_final(
    const float* __restrict__ rewards, const float* __restrict__ values,
    const float* __restrict__ next_values, const void* __restrict__ term,
    const void* __restrict__ trunc, const float* __restrict__ lp,
    const float* __restrict__ olp, const float2* __restrict__ E2,
    const float2* __restrict__ blockAgg, const float4* __restrict__ bs4,
    const float* __restrict__ bs1, float* __restrict__ out, int n, int nb)
{
    __shared__ int flg[2];
    __shared__ float sA[BLOCK], sB[BLOCK];
    __shared__ float sS[MAXNB];
    __shared__ double dS[BLOCK], dS2[BLOCK];
    __shared__ float statMean, statInv;

    const int t = threadIdx.x;
    const int bid = blockIdx.x;
    const int mode = detect_mode(term, n, flg);
    const long base = (long)bid * CHUNK + (long)t * ITEMS;

    float c[ITEMS], d[ITEMS], v[ITEMS];
    compute_cd(rewards, values, next_values, term, trunc, mode, base, n, c, d, v);
    float2 e = E2[(long)bid * BLOCK + t];

    float la[4], lb[4];
#pragma unroll
    for (int j = 0; j < 4; ++j) {
        int i = 4 * t + j;
        if (i < nb) { float2 f = blockAgg[i]; la[j] = f.x; lb[j] = f.y; }
        else        { la[j] = 1.f; lb[j] = 0.f; }
    }
    float a = 1.f, b = 0.f;
#pragma unroll
    for (int j = 3; j >= 0; --j) { b = fmaf(la[j], b, lb[j]); a *= la[j]; }
    sA[t] = a; sB[t] = b;
    __syncthreads();
    for (int dd = 1; dd < BLOCK; dd <<= 1) {
        float ra = 1.f, rb = 0.f;
        if (t + dd < BLOCK) { ra = sA[t + dd]; rb = sB[t + dd]; }
        __syncthreads();
        b = fmaf(a, rb, b);
        a *= ra;
        sA[t] = a; sB[t] = b;
        __syncthreads();
    }
    float x = (t + 1 < BLOCK) ? sB[t + 1] : 0.f;
    double ds = 0.0, ds2 = 0.0;
#pragma unroll
    for (int j = 3; j >= 0; --j) {
        int i = 4 * t + j;
        if (i < nb) {
            sS[i] = x;
            float4 s4 = bs4[i];
            double xd = (double)x;
            ds  += (double)s4.x * xd + (double)s4.y;
            ds2 += (double)s4.z * xd * xd + 2.0 * (double)s4.w * xd + (double)bs1[i];
        }
        x = fmaf(la[j], x, lb[j]);
    }
    dS[t] = ds; dS2[t] = ds2;
    __syncthreads();
    for (int dd = BLOCK / 2; dd > 0; dd >>= 1) {
        if (t < dd) { dS[t] += dS[t + dd]; dS2[t] += dS2[t + dd]; }
        __syncthreads();
    }
    if (t == 0) {
        double sum = dS[0], sumsq = dS2[0];
        double mean = sum / (double)n;
        double var = (sumsq - sum * sum / (double)n) / (double)(n - 1);
        if (var < 0.0) var = 0.0;
        statMean = (float)mean;
        statInv  = 1.0f / ((float)sqrt(var) + 1e-9f);
    }
    __syncthreads();

    float xx = fmaf(e.x, sS[bid], e.y);
    float adv[ITEMS];
#pragma unroll
    for (int j = ITEMS - 1; j >= 0; --j) {
        xx = fmaf(c[j], xx, d[j]);
        adv[j] = xx;
    }
    const float mean = statMean;
    const float inv  = statInv;
    if (base + ITEMS <= n) {
        float l[ITEMS], o[ITEMS];
        const float4* l4 = (const float4*)(lp + base);
        const float4* o4 = (const float4*)(olp + base);
#pragma unroll
        for (int k = 0; k < 2; ++k) {
            float4 q = l4[k]; l[4*k]=q.x; l[4*k+1]=q.y; l[4*k+2]=q.z; l[4*k+3]=q.w;
            float4 w = o4[k]; o[4*k]=w.x; o[4*k+1]=w.y; o[4*k+2]=w.z; o[4*k+3]=w.w;
        }
        float buf[3 * ITEMS];
#pragma unroll
        for (int j = 0; j < ITEMS; ++j) {
            float an = (adv[j] - mean) * inv;
            float ratio = expf(l[j] - o[j]);
            float cl = fminf(fmaxf(ratio, 0.8f), 1.2f);
            buf[3*j]     = an;
            buf[3*j + 1] = adv[j] + v[j];
            buf[3*j + 2] = -fminf(ratio * an, cl * an);
        }
        float4* dst = (float4*)(out + 3 * base);
#pragma unroll
        for (int k = 0; k < 6; ++k)
            dst[k] = make_float4(buf[4*k], buf[4*k+1], buf[4*k+2], buf[4*k+3]);
    } else {
        for (int j = 0; j < ITEMS; ++j) {
            long i = base + j;
            if (i < (long)n) {
                float an = (adv[j] - mean) * inv;
                float ratio = expf(lp[i] - olp[i]);
                float cl = fminf(fmaxf(ratio, 0.8f), 1.2f);
                out[3*i]     = an;
                out[3*i + 1] = adv[j] + v[j];
                out[3*i + 2] = -fminf(ratio * an, cl * an);
            }
        }
    }
}

extern "C" void kernel_launch(void* const* d_in, const int* in_sizes, int n_in,
                              void* d_out, int out_size, void* d_ws, size_t ws_size,
                              hipStream_t stream) {
    const float* rewards     = (const float*)d_in[0];
    const float* values      = (const float*)d_in[1];
    const float* next_values = (const float*)d_in[2];
    const float* lp          = (const float*)d_in[3];
    const float* olp         = (const float*)d_in[4];
    const void*  term        = d_in[5];
    const void*  trunc       = d_in[6];
    float* out = (float*)d_out;
    int n = in_sizes[0];
    int nb = (n + CHUNK - 1) / CHUNK;   // 1024 for N=2^21; must be <= MAXNB

    char* ws = (char*)d_ws;
    float2* blockAgg = (float2*)ws;                                   // 8 KB
    float4* bs4      = (float4*)(ws + MAXNB * 8);                     // 16 KB
    float*  bs1      = (float*) (ws + MAXNB * 8 + MAXNB * 16);        // 4 KB
    int*    flags    = (int*)  (ws + MAXNB * 28);                     // 4 KB
    float2* E2       = (float2*)(ws + MAXNB * 28 + 4096 + 256);       // 2 MB (fallback only)

    // clear barrier flags (workspace is re-poisoned between iterations);
    // 4 KB memset node — graph-capture safe, ~2-3 µs dispatch
    hipMemsetAsync(flags, 0, (size_t)nb * sizeof(int), stream);

    void* kargs[] = {
        (void*)&rewards, (void*)&values, (void*)&next_values, (void*)&lp,
        (void*)&olp, (void*)&term, (void*)&trunc, (void*)&blockAgg,
        (void*)&bs4, (void*)&bs1, (void*)&flags, (void*)&out, (void*)&n, (void*)&nb
    };
    hipError_t err = hipLaunchCooperativeKernel(
        (const void*)k_fused, dim3((unsigned)nb), dim3(BLOCK), kargs, 0, stream);

    if (err != hipSuccess) {
        // proven 2-kernel fallback
        k1_agg <<<nb, BLOCK, 0, stream>>>(rewards, values, next_values, term, trunc,
                                          blockAgg, E2, bs4, bs1, n);
        k3_final<<<nb, BLOCK, 0, stream>>>(rewards, values, next_values, term, trunc,
                                           lp, olp, E2, blockAgg, bs4, bs1, out, n, nb);
    }
}

// Round 4
// 200.561 us; speedup vs baseline: 2.6520x; 2.6520x over previous
//
#include <hip/hip_runtime.h>
#include <stdint.h>

static constexpr int BLOCK = 256;
static constexpr int ITEMS = 8;
static constexpr int CHUNK = BLOCK * ITEMS;   // 2048 elements per block
static constexpr int MAXNB = 1024;            // 1024 * 2048 = 2097152 = N

#define GAMMA_F 0.99f
static __device__ __forceinline__ float gl_const() { return (float)(0.99 * 0.95); }

// agent-scope fences: __hip_atomic_fence is not in this ROCm's headers;
// __builtin_amdgcn_fence(order, "agent") is the clang-native equivalent.
#define FENCE_REL_AGENT() __builtin_amdgcn_fence(__ATOMIC_RELEASE, "agent")
#define FENCE_ACQ_AGENT() __builtin_amdgcn_fence(__ATOMIC_ACQUIRE, "agent")

// affine compose: self ∘ right (right applied first): x -> a1*(a2*x+b2)+b1
__device__ __forceinline__ void compose(float& a1, float& b1, float a2, float b2) {
    b1 = fmaf(a1, b2, b1);
    a1 = a1 * a2;
}

// ---------------- bool dtype runtime probe ----------------
// 0 = int32, 1 = uint8/bool, 2 = float32. Byte pattern of first 1024 bytes.
__device__ __forceinline__ int detect_mode(const void* term, int n_elems, int* flg) {
    int t = threadIdx.x;
    if (t == 0) { flg[0] = 0; flg[1] = 0; }
    __syncthreads();
    if (t < 256) {
        const unsigned char* p = (const unsigned char*)term;
        int i0 = 4 * t;
        if (i0 + 3 < n_elems) {
            unsigned b1 = p[i0 + 1], b2 = p[i0 + 2], b3 = p[i0 + 3];
            if (b1) atomicOr(&flg[0], 1);
            if (b2 | b3) atomicOr(&flg[1], 1);
        }
    }
    __syncthreads();
    return flg[0] ? 1 : (flg[1] ? 2 : 0);
}

__device__ __forceinline__ int load_bool1(const void* p, long i, int mode) {
    if (mode == 1) return ((const unsigned char*)p)[i] != 0;
    if (mode == 0) return ((const int*)p)[i] != 0;
    return ((const float*)p)[i] != 0.0f;
}

__device__ __forceinline__ void load_bool8(const void* p, long base, int mode, int* f) {
    if (mode == 1) {
        uint2 q = *(const uint2*)((const unsigned char*)p + base);
        unsigned w[2] = {q.x, q.y};
#pragma unroll
        for (int j = 0; j < 8; ++j) f[j] = (int)((w[j >> 2] >> ((j & 3) * 8)) & 0xffu);
    } else if (mode == 0) {
        const int4* q = (const int4*)((const int*)p + base);
#pragma unroll
        for (int k = 0; k < 2; ++k) {
            int4 v = q[k];
            f[4*k] = v.x; f[4*k+1] = v.y; f[4*k+2] = v.z; f[4*k+3] = v.w;
        }
    } else {
        const float4* q = (const float4*)((const float*)p + base);
#pragma unroll
        for (int k = 0; k < 2; ++k) {
            float4 v = q[k];
            f[4*k] = v.x != 0.f; f[4*k+1] = v.y != 0.f; f[4*k+2] = v.z != 0.f; f[4*k+3] = v.w != 0.f;
        }
    }
}

// c[j] = not_done * gamma*lambda ; d[j] = r + gamma*not_term*nv - v
__device__ __forceinline__ void compute_cd(
    const float* __restrict__ rewards, const float* __restrict__ values,
    const float* __restrict__ next_values, const void* __restrict__ term,
    const void* __restrict__ trunc, int mode, long base, int n,
    float* c, float* d, float* v)
{
    const float GL = gl_const();
    if (base + ITEMS <= n) {
        float r[ITEMS], nv[ITEMS];
        const float4* r4 = (const float4*)(rewards + base);
        const float4* v4 = (const float4*)(values + base);
        const float4* n4 = (const float4*)(next_values + base);
#pragma unroll
        for (int k = 0; k < 2; ++k) {
            float4 a = r4[k]; r[4*k]=a.x; r[4*k+1]=a.y; r[4*k+2]=a.z; r[4*k+3]=a.w;
            float4 b = v4[k]; v[4*k]=b.x; v[4*k+1]=b.y; v[4*k+2]=b.z; v[4*k+3]=b.w;
            float4 q = n4[k]; nv[4*k]=q.x; nv[4*k+1]=q.y; nv[4*k+2]=q.z; nv[4*k+3]=q.w;
        }
        int tm[ITEMS], tr[ITEMS];
        load_bool8(term,  base, mode, tm);
        load_bool8(trunc, base, mode, tr);
#pragma unroll
        for (int j = 0; j < ITEMS; ++j) {
            float nt = tm[j] ? 0.f : 1.f;
            float nd = (tm[j] | tr[j]) ? 0.f : 1.f;
            d[j] = r[j] + GAMMA_F * nt * nv[j] - v[j];
            c[j] = nd * GL;
        }
    } else {
#pragma unroll
        for (int j = 0; j < ITEMS; ++j) {
            long i = base + j;
            if (i < (long)n) {
                int tm = load_bool1(term, i, mode);
                int tr = load_bool1(trunc, i, mode);
                float nt = tm ? 0.f : 1.f;
                float nd = (tm | tr) ? 0.f : 1.f;
                v[j] = values[i];
                d[j] = rewards[i] + GAMMA_F * nt * next_values[i] - v[j];
                c[j] = nd * GL;
            } else { c[j] = 1.f; d[j] = 0.f; v[j] = 0.f; }
        }
    }
}

// ================= FUSED kernel, HIERARCHICAL flag barrier v3 =================
// Round-1: cg::grid.sync() = 1024 serialized same-address RMW atomics -> 210 µs.
// Round-2: 262144 threads spinning agent-scope ACQUIRE loads -> L3 poll storm,
//          405 µs, convoying the release stores.
// v3: pollers reduced 256x. Arrival: each block's t0 release-stores a DISTINCT
// flag. Only block 0's 256 threads poll the <=1024 arrival flags (relaxed).
// Block 0 then release-stores ONE "go" flag; each other block polls go with a
// SINGLE thread (relaxed + s_sleep), then one block-wide acquire fence.
// No RMW anywhere; poll traffic ~1.3K threads instead of 262K.
__global__ __launch_bounds__(BLOCK, 4) void k_fused(
    const float* __restrict__ rewards, const float* __restrict__ values,
    const float* __restrict__ next_values, const float* __restrict__ lp,
    const float* __restrict__ olp, const void* __restrict__ term,
    const void* __restrict__ trunc, float2* __restrict__ blockAgg,
    float4* __restrict__ bs4, float* __restrict__ bs1, int* __restrict__ flags,
    float* __restrict__ out, int n, int nb)
{
    __shared__ int flg[2];
    __shared__ float wA[4], wB[4];
    __shared__ float red[4][5];
    __shared__ float sA[BLOCK], sB[BLOCK];
    __shared__ float sS[MAXNB];
    __shared__ double dS[BLOCK], dS2[BLOCK];
    __shared__ float statMean, statInv;

    const int t = threadIdx.x;
    const int lane = t & 63, w = t >> 6;
    const int bid = blockIdx.x;
    const int mode = detect_mode(term, n, flg);
    const long base = (long)bid * CHUNK + (long)t * ITEMS;
    int* const go = flags + MAXNB;

    float c[ITEMS], d[ITEMS], v[ITEMS];
    compute_cd(rewards, values, next_values, term, trunc, mode, base, n, c, d, v);

    // pack c into 2 masks so c[] need not live across the barrier (spill fix):
    // cm bit j: c[j]==GL ; idm bit j: c[j]==1 (OOB identity). c[j]==0 otherwise.
    unsigned cm = 0, idm = 0;
#pragma unroll
    for (int j = 0; j < ITEMS; ++j) {
        if (c[j] != 0.f) { if (c[j] == 1.f) idm |= (1u << j); else cm |= (1u << j); }
    }

    // ---- phase 1: thread-serial affine aggregate of this thread's 8 items ----
    float a = 1.f, b = 0.f;
#pragma unroll
    for (int j = ITEMS - 1; j >= 0; --j) { b = fmaf(c[j], b, d[j]); a *= c[j]; }

    // wave suffix-inclusive scan via shuffles: H_l = F_l ∘ ... ∘ F_63
#pragma unroll
    for (int dd = 1; dd < 64; dd <<= 1) {
        float ra = __shfl_down(a, dd, 64);
        float rb = __shfl_down(b, dd, 64);
        if (lane + dd < 64) { b = fmaf(a, rb, b); a *= ra; }
    }
    if (lane == 0) { wA[w] = a; wB[w] = b; }   // wave aggregate
    // within-wave exclusive entry E = H_{l+1} (identity at lane 63)
    float ea = __shfl_down(a, 1, 64);
    float eb = __shfl_down(b, 1, 64);
    if (lane == 63) { ea = 1.f; eb = 0.f; }
    __syncthreads();
    // compose with later-wave aggregates (ea,eb stays in registers — no E2)
    for (int ww = w + 1; ww < 4; ++ww) compose(ea, eb, wA[ww], wB[ww]);
    if (t == 0) {
        float Aa = wA[0], Ab = wB[0];
        for (int ww = 1; ww < 4; ++ww) compose(Aa, Ab, wA[ww], wB[ww]);
        blockAgg[bid] = make_float2(Aa, Ab);
    }

    // symbolic replay: adv_j = p*x_b + q ; accumulate 5 moment scalars
    {
        float p = ea, q = eb;
        float sP = 0.f, sQ = 0.f, sP2 = 0.f, sPQ = 0.f, sQ2 = 0.f;
#pragma unroll
        for (int j = ITEMS - 1; j >= 0; --j) {
            p = c[j] * p;
            q = fmaf(c[j], q, d[j]);
            if (base + j < (long)n) {
                sP += p; sQ += q; sP2 += p*p; sPQ += p*q; sQ2 += q*q;
            }
        }
#pragma unroll
        for (int dd = 32; dd > 0; dd >>= 1) {
            sP  += __shfl_down(sP,  dd, 64);
            sQ  += __shfl_down(sQ,  dd, 64);
            sP2 += __shfl_down(sP2, dd, 64);
            sPQ += __shfl_down(sPQ, dd, 64);
            sQ2 += __shfl_down(sQ2, dd, 64);
        }
        if (lane == 0) { red[w][0]=sP; red[w][1]=sQ; red[w][2]=sP2; red[w][3]=sPQ; red[w][4]=sQ2; }
        __syncthreads();
        if (t == 0) {
            float m0=0,m1=0,m2=0,m3=0,m4=0;
            for (int ww = 0; ww < 4; ++ww) { m0+=red[ww][0]; m1+=red[ww][1]; m2+=red[ww][2]; m3+=red[ww][3]; m4+=red[ww][4]; }
            bs4[bid] = make_float4(m0, m1, m2, m3);
            bs1[bid] = m4;
        }
    }

    // ---- hierarchical grid barrier (no RMW, ~1.3K pollers total) ----
    // arrival: only t0's global writes (blockAgg/bs4/bs1) matter cross-block.
    if (t == 0) {
        FENCE_REL_AGENT();   // write-back this block's aggregates to L3
        __hip_atomic_store(&flags[bid], 1, __ATOMIC_RELAXED, __HIP_MEMORY_SCOPE_AGENT);
    }
    if (bid == 0) {
        // 256 threads poll <=4 distinct flags each (relaxed, short sleep)
#pragma unroll
        for (int j = 0; j < 4; ++j) {
            int i = (t << 2) | j;
            if (i < nb) {
                while (__hip_atomic_load(&flags[i], __ATOMIC_RELAXED, __HIP_MEMORY_SCOPE_AGENT) == 0)
                    __builtin_amdgcn_s_sleep(1);
            }
        }
        __syncthreads();
        if (t == 0) {
            FENCE_REL_AGENT();
            __hip_atomic_store(go, 1, __ATOMIC_RELAXED, __HIP_MEMORY_SCOPE_AGENT);
        }
    } else {
        if (t == 0) {
            while (__hip_atomic_load(go, __ATOMIC_RELAXED, __HIP_MEMORY_SCOPE_AGENT) == 0)
                __builtin_amdgcn_s_sleep(8);
        }
    }
    __syncthreads();
    // one block-wide acquire fence: invalidate stale L1 lines before reading
    // the other blocks' aggregates (pushed to L3 by their release fences)
    FENCE_ACQ_AGENT();
    __syncthreads();

    // ---- phase 2: redundant per-block suffix scan of nb aggregates + stats ----
    float la[4], lb[4];
#pragma unroll
    for (int j = 0; j < 4; ++j) {
        int i = 4 * t + j;
        if (i < nb) { float2 f = blockAgg[i]; la[j] = f.x; lb[j] = f.y; }
        else        { la[j] = 1.f; lb[j] = 0.f; }
    }
    a = 1.f; b = 0.f;
#pragma unroll
    for (int j = 3; j >= 0; --j) { b = fmaf(la[j], b, lb[j]); a *= la[j]; }
    sA[t] = a; sB[t] = b;
    __syncthreads();
    for (int dd = 1; dd < BLOCK; dd <<= 1) {
        float ra = 1.f, rb = 0.f;
        if (t + dd < BLOCK) { ra = sA[t + dd]; rb = sB[t + dd]; }
        __syncthreads();
        b = fmaf(a, rb, b);
        a *= ra;
        sA[t] = a; sB[t] = b;
        __syncthreads();
    }
    {
        float x = (t + 1 < BLOCK) ? sB[t + 1] : 0.f;   // suffix entering block 4t+3
        double ds = 0.0, ds2 = 0.0;
#pragma unroll
        for (int j = 3; j >= 0; --j) {
            int i = 4 * t + j;
            if (i < nb) {
                sS[i] = x;
                float4 s4 = bs4[i];
                double xd = (double)x;
                ds  += (double)s4.x * xd + (double)s4.y;
                ds2 += (double)s4.z * xd * xd + 2.0 * (double)s4.w * xd + (double)bs1[i];
            }
            x = fmaf(la[j], x, lb[j]);
        }
        dS[t] = ds; dS2[t] = ds2;
    }
    __syncthreads();
    for (int dd = BLOCK / 2; dd > 0; dd >>= 1) {
        if (t < dd) { dS[t] += dS[t + dd]; dS2[t] += dS2[t + dd]; }
        __syncthreads();
    }
    if (t == 0) {
        double sum = dS[0], sumsq = dS2[0];
        double mean = sum / (double)n;
        double var = (sumsq - sum * sum / (double)n) / (double)(n - 1);
        if (var < 0.0) var = 0.0;
        statMean = (float)mean;
        statInv  = 1.0f / ((float)sqrt(var) + 1e-9f);
    }
    __syncthreads();

    // ---- phase 3: replay from masks + finalize (d,v,ea,eb,cm,idm live) ----
    const float GL = gl_const();
    float xx = fmaf(ea, sS[bid], eb);
    float adv[ITEMS];
#pragma unroll
    for (int j = ITEMS - 1; j >= 0; --j) {
        float nx = ((cm >> j) & 1u) ? fmaf(GL, xx, d[j]) : d[j];
        if ((idm >> j) & 1u) nx = xx;          // OOB identity (tail only)
        xx = nx;
        adv[j] = xx;
    }
    const float mean = statMean;
    const float inv  = statInv;
    if (base + ITEMS <= n) {
        float l[ITEMS], o[ITEMS];
        const float4* l4 = (const float4*)(lp + base);
        const float4* o4 = (const float4*)(olp + base);
#pragma unroll
        for (int k = 0; k < 2; ++k) {
            float4 q = l4[k]; l[4*k]=q.x; l[4*k+1]=q.y; l[4*k+2]=q.z; l[4*k+3]=q.w;
            float4 ww = o4[k]; o[4*k]=ww.x; o[4*k+1]=ww.y; o[4*k+2]=ww.z; o[4*k+3]=ww.w;
        }
        float buf[3 * ITEMS];
#pragma unroll
        for (int j = 0; j < ITEMS; ++j) {
            float an = (adv[j] - mean) * inv;
            float ratio = expf(l[j] - o[j]);
            float cl = fminf(fmaxf(ratio, 0.8f), 1.2f);
            buf[3*j]     = an;
            buf[3*j + 1] = adv[j] + v[j];
            buf[3*j + 2] = -fminf(ratio * an, cl * an);
        }
        float4* dst = (float4*)(out + 3 * base);   // 3*base % 4 == 0 → 16B aligned
#pragma unroll
        for (int k = 0; k < 6; ++k)
            dst[k] = make_float4(buf[4*k], buf[4*k+1], buf[4*k+2], buf[4*k+3]);
    } else {
        for (int j = 0; j < ITEMS; ++j) {
            long i = base + j;
            if (i < (long)n) {
                float an = (adv[j] - mean) * inv;
                float ratio = expf(lp[i] - olp[i]);
                float cl = fminf(fmaxf(ratio, 0.8f), 1.2f);
                out[3*i]     = an;
                out[3*i + 1] = adv[j] + v[j];
                out[3*i + 2] = -fminf(ratio * an, cl * an);
            }
        }
    }
}

// ================= fallback 2-kernel path (proven; used only if coop fails) ==
__global__ __launch_bounds__(BLOCK) void k1_agg(
    const float* __restrict__ rewards, const float* __restrict__ values,
    const float* __restrict__ next_values, const void* __restrict__ term,
    const void* __restrict__ trunc, float2* __restrict__ blockAgg,
    float2* __restrict__ E2, float4* __restrict__ bs4, float* __restrict__ bs1,
    int n)
{
    __shared__ int flg[2];
    __shared__ float wA[4], wB[4];
    __shared__ float red[4][5];

    const int t = threadIdx.x;
    const int lane = t & 63, w = t >> 6;
    const int bid = blockIdx.x;
    const int mode = detect_mode(term, n, flg);
    const long base = (long)bid * CHUNK + (long)t * ITEMS;

    float c[ITEMS], d[ITEMS], v[ITEMS];
    compute_cd(rewards, values, next_values, term, trunc, mode, base, n, c, d, v);

    float a = 1.f, b = 0.f;
#pragma unroll
    for (int j = ITEMS - 1; j >= 0; --j) { b = fmaf(c[j], b, d[j]); a *= c[j]; }

#pragma unroll
    for (int dd = 1; dd < 64; dd <<= 1) {
        float ra = __shfl_down(a, dd, 64);
        float rb = __shfl_down(b, dd, 64);
        if (lane + dd < 64) { b = fmaf(a, rb, b); a *= ra; }
    }
    if (lane == 0) { wA[w] = a; wB[w] = b; }
    float ea = __shfl_down(a, 1, 64);
    float eb = __shfl_down(b, 1, 64);
    if (lane == 63) { ea = 1.f; eb = 0.f; }
    __syncthreads();
    for (int ww = w + 1; ww < 4; ++ww) compose(ea, eb, wA[ww], wB[ww]);
    if (t == 0) {
        float Aa = wA[0], Ab = wB[0];
        for (int ww = 1; ww < 4; ++ww) compose(Aa, Ab, wA[ww], wB[ww]);
        blockAgg[bid] = make_float2(Aa, Ab);
    }
    E2[(long)bid * BLOCK + t] = make_float2(ea, eb);

    float p = ea, q = eb;
    float sP = 0.f, sQ = 0.f, sP2 = 0.f, sPQ = 0.f, sQ2 = 0.f;
#pragma unroll
    for (int j = ITEMS - 1; j >= 0; --j) {
        p = c[j] * p;
        q = fmaf(c[j], q, d[j]);
        if (base + j < (long)n) {
            sP += p; sQ += q; sP2 += p*p; sPQ += p*q; sQ2 += q*q;
        }
    }
#pragma unroll
    for (int dd = 32; dd > 0; dd >>= 1) {
        sP  += __shfl_down(sP,  dd, 64);
        sQ  += __shfl_down(sQ,  dd, 64);
        sP2 += __shfl_down(sP2, dd, 64);
        sPQ += __shfl_down(sPQ, dd, 64);
        sQ2 += __shfl_down(sQ2, dd, 64);
    }
    if (lane == 0) { red[w][0]=sP; red[w][1]=sQ; red[w][2]=sP2; red[w][3]=sPQ; red[w][4]=sQ2; }
    __syncthreads();
    if (t == 0) {
        float m0=0,m1=0,m2=0,m3=0,m4=0;
        for (int ww = 0; ww < 4; ++ww) { m0+=red[ww][0]; m1+=red[ww][1]; m2+=red[ww][2]; m3+=red[ww][3]; m4+=red[ww][4]; }
        bs4[bid] = make_float4(m0, m1, m2, m3);
        bs1[bid] = m4;
    }
}

__global__ __launch_bounds__(BLOCK) void k3_final(
    const float* __restrict__ rewards, const float* __restrict__ values,
    const float* __restrict__ next_values, const void* __restrict__ term,
    const void* __restrict__ trunc, const float* __restrict__ lp,
    const float* __restrict__ olp, const float2* __restrict__ E2,
    const float2* __restrict__ blockAgg, const float4* __restrict__ bs4,
    const float* __restrict__ bs1, float* __restrict__ out, int n, int nb)
{
    __shared__ int flg[2];
    __shared__ float sA[BLOCK], sB[BLOCK];
    __shared__ float sS[MAXNB];
    __shared__ double dS[BLOCK], dS2[BLOCK];
    __shared__ float statMean, statInv;

    const int t = threadIdx.x;
    const int bid = blockIdx.x;
    const int mode = detect_mode(term, n, flg);
    const long base = (long)bid * CHUNK + (long)t * ITEMS;

    float c[ITEMS], d[ITEMS], v[ITEMS];
    compute_cd(rewards, values, next_values, term, trunc, mode, base, n, c, d, v);
    float2 e = E2[(long)bid * BLOCK + t];

    float la[4], lb[4];
#pragma unroll
    for (int j = 0; j < 4; ++j) {
        int i = 4 * t + j;
        if (i < nb) { float2 f = blockAgg[i]; la[j] = f.x; lb[j] = f.y; }
        else        { la[j] = 1.f; lb[j] = 0.f; }
    }
    float a = 1.f, b = 0.f;
#pragma unroll
    for (int j = 3; j >= 0; --j) { b = fmaf(la[j], b, lb[j]); a *= la[j]; }
    sA[t] = a; sB[t] = b;
    __syncthreads();
    for (int dd = 1; dd < BLOCK; dd <<= 1) {
        float ra = 1.f, rb = 0.f;
        if (t + dd < BLOCK) { ra = sA[t + dd]; rb = sB[t + dd]; }
        __syncthreads();
        b = fmaf(a, rb, b);
        a *= ra;
        sA[t] = a; sB[t] = b;
        __syncthreads();
    }
    float x = (t + 1 < BLOCK) ? sB[t + 1] : 0.f;
    double ds = 0.0, ds2 = 0.0;
#pragma unroll
    for (int j = 3; j >= 0; --j) {
        int i = 4 * t + j;
        if (i < nb) {
            sS[i] = x;
            float4 s4 = bs4[i];
            double xd = (double)x;
            ds  += (double)s4.x * xd + (double)s4.y;
            ds2 += (double)s4.z * xd * xd + 2.0 * (double)s4.w * xd + (double)bs1[i];
        }
        x = fmaf(la[j], x, lb[j]);
    }
    dS[t] = ds; dS2[t] = ds2;
    __syncthreads();
    for (int dd = BLOCK / 2; dd > 0; dd >>= 1) {
        if (t < dd) { dS[t] += dS[t + dd]; dS2[t] += dS2[t + dd]; }
        __syncthreads();
    }
    if (t == 0) {
        double sum = dS[0], sumsq = dS2[0];
        double mean = sum / (double)n;
        double var = (sumsq - sum * sum / (double)n) / (double)(n - 1);
        if (var < 0.0) var = 0.0;
        statMean = (float)mean;
        statInv  = 1.0f / ((float)sqrt(var) + 1e-9f);
    }
    __syncthreads();

    float xx = fmaf(e.x, sS[bid], e.y);
    float adv[ITEMS];
#pragma unroll
    for (int j = ITEMS - 1; j >= 0; --j) {
        xx = fmaf(c[j], xx, d[j]);
        adv[j] = xx;
    }
    const float mean = statMean;
    const float inv  = statInv;
    if (base + ITEMS <= n) {
        float l[ITEMS], o[ITEMS];
        const float4* l4 = (const float4*)(lp + base);
        const float4* o4 = (const float4*)(olp + base);
#pragma unroll
        for (int k = 0; k < 2; ++k) {
            float4 q = l4[k]; l[4*k]=q.x; l[4*k+1]=q.y; l[4*k+2]=q.z; l[4*k+3]=q.w;
            float4 w = o4[k]; o[4*k]=w.x; o[4*k+1]=w.y; o[4*k+2]=w.z; o[4*k+3]=w.w;
        }
        float buf[3 * ITEMS];
#pragma unroll
        for (int j = 0; j < ITEMS; ++j) {
            float an = (adv[j] - mean) * inv;
            float ratio = expf(l[j] - o[j]);
            float cl = fminf(fmaxf(ratio, 0.8f), 1.2f);
            buf[3*j]     = an;
            buf[3*j + 1] = adv[j] + v[j];
            buf[3*j + 2] = -fminf(ratio * an, cl * an);
        }
        float4* dst = (float4*)(out + 3 * base);
#pragma unroll
        for (int k = 0; k < 6; ++k)
            dst[k] = make_float4(buf[4*k], buf[4*k+1], buf[4*k+2], buf[4*k+3]);
    } else {
        for (int j = 0; j < ITEMS; ++j) {
            long i = base + j;
            if (i < (long)n) {
                float an = (adv[j] - mean) * inv;
                float ratio = expf(lp[i] - olp[i]);
                float cl = fminf(fmaxf(ratio, 0.8f), 1.2f);
                out[3*i]     = an;
                out[3*i + 1] = adv[j] + v[j];
                out[3*i + 2] = -fminf(ratio * an, cl * an);
            }
        }
    }
}

extern "C" void kernel_launch(void* const* d_in, const int* in_sizes, int n_in,
                              void* d_out, int out_size, void* d_ws, size_t ws_size,
                              hipStream_t stream) {
    const float* rewards     = (const float*)d_in[0];
    const float* values      = (const float*)d_in[1];
    const float* next_values = (const float*)d_in[2];
    const float* lp          = (const float*)d_in[3];
    const float* olp         = (const float*)d_in[4];
    const void*  term        = d_in[5];
    const void*  trunc       = d_in[6];
    float* out = (float*)d_out;
    int n = in_sizes[0];
    int nb = (n + CHUNK - 1) / CHUNK;   // 1024 for N=2^21; must be <= MAXNB

    char* ws = (char*)d_ws;
    float2* blockAgg = (float2*)ws;                                   // 8 KB
    float4* bs4      = (float4*)(ws + MAXNB * 8);                     // 16 KB
    float*  bs1      = (float*) (ws + MAXNB * 8 + MAXNB * 16);        // 4 KB
    int*    flags    = (int*)  (ws + MAXNB * 28);                     // (MAXNB+1) ints
    float2* E2       = (float2*)(ws + MAXNB * 28 + 8192);             // 2 MB (fallback only)

    // clear arrival flags + go flag (workspace is re-poisoned between iters);
    // (MAXNB+1)*4 = 4100 B memset node — graph-capture safe
    (void)hipMemsetAsync(flags, 0, (size_t)(MAXNB + 1) * sizeof(int), stream);

    void* kargs[] = {
        (void*)&rewards, (void*)&values, (void*)&next_values, (void*)&lp,
        (void*)&olp, (void*)&term, (void*)&trunc, (void*)&blockAgg,
        (void*)&bs4, (void*)&bs1, (void*)&flags, (void*)&out, (void*)&n, (void*)&nb
    };
    hipError_t err = hipLaunchCooperativeKernel(
        (const void*)k_fused, dim3((unsigned)nb), dim3(BLOCK), kargs, 0, stream);

    if (err != hipSuccess) {
        // proven 2-kernel fallback
        k1_agg <<<nb, BLOCK, 0, stream>>>(rewards, values, next_values, term, trunc,
                                          blockAgg, E2, bs4, bs1, n);
        k3_final<<<nb, BLOCK, 0, stream>>>(rewards, values, next_values, term, trunc,
                                           lp, olp, E2, blockAgg, bs4, bs1, out, n, nb);
    }
}

// Round 5
// 128.318 us; speedup vs baseline: 4.1451x; 1.5630x over previous
//
#include <hip/hip_runtime.h>
#include <stdint.h>

static constexpr int BLOCK = 256;
static constexpr int ITEMS = 8;
static constexpr int CHUNK = BLOCK * ITEMS;   // 2048 elements per block
static constexpr int MAXNB = 1024;            // 1024 * 2048 = 2097152 = N

#define GAMMA_F 0.99f
static __device__ __forceinline__ float gl_const() { return (float)(0.99 * 0.95); }

// affine compose: self ∘ right (right applied first): x -> a1*(a2*x+b2)+b1
__device__ __forceinline__ void compose(float& a1, float& b1, float a2, float b2) {
    b1 = fmaf(a1, b2, b1);
    a1 = a1 * a2;
}

// ---------------- bool dtype runtime probe ----------------
// 0 = int32, 1 = uint8/bool, 2 = float32. Byte pattern of first 1024 bytes.
__device__ __forceinline__ int detect_mode(const void* term, int n_elems, int* flg) {
    int t = threadIdx.x;
    if (t == 0) { flg[0] = 0; flg[1] = 0; }
    __syncthreads();
    if (t < 256) {
        const unsigned char* p = (const unsigned char*)term;
        int i0 = 4 * t;
        if (i0 + 3 < n_elems) {
            unsigned b1 = p[i0 + 1], b2 = p[i0 + 2], b3 = p[i0 + 3];
            if (b1) atomicOr(&flg[0], 1);
            if (b2 | b3) atomicOr(&flg[1], 1);
        }
    }
    __syncthreads();
    return flg[0] ? 1 : (flg[1] ? 2 : 0);
}

__device__ __forceinline__ int load_bool1(const void* p, long i, int mode) {
    if (mode == 1) return ((const unsigned char*)p)[i] != 0;
    if (mode == 0) return ((const int*)p)[i] != 0;
    return ((const float*)p)[i] != 0.0f;
}

__device__ __forceinline__ void load_bool8(const void* p, long base, int mode, int* f) {
    if (mode == 1) {
        uint2 q = *(const uint2*)((const unsigned char*)p + base);
        unsigned w[2] = {q.x, q.y};
#pragma unroll
        for (int j = 0; j < 8; ++j) f[j] = (int)((w[j >> 2] >> ((j & 3) * 8)) & 0xffu);
    } else if (mode == 0) {
        const int4* q = (const int4*)((const int*)p + base);
#pragma unroll
        for (int k = 0; k < 2; ++k) {
            int4 v = q[k];
            f[4*k] = v.x; f[4*k+1] = v.y; f[4*k+2] = v.z; f[4*k+3] = v.w;
        }
    } else {
        const float4* q = (const float4*)((const float*)p + base);
#pragma unroll
        for (int k = 0; k < 2; ++k) {
            float4 v = q[k];
            f[4*k] = v.x != 0.f; f[4*k+1] = v.y != 0.f; f[4*k+2] = v.z != 0.f; f[4*k+3] = v.w != 0.f;
        }
    }
}

// c[j] = not_done * gamma*lambda ; d[j] = r + gamma*not_term*nv - v
__device__ __forceinline__ void compute_cd(
    const float* __restrict__ rewards, const float* __restrict__ values,
    const float* __restrict__ next_values, const void* __restrict__ term,
    const void* __restrict__ trunc, int mode, long base, int n,
    float* c, float* d, float* v)
{
    const float GL = gl_const();
    if (base + ITEMS <= n) {
        float r[ITEMS], nv[ITEMS];
        const float4* r4 = (const float4*)(rewards + base);
        const float4* v4 = (const float4*)(values + base);
        const float4* n4 = (const float4*)(next_values + base);
#pragma unroll
        for (int k = 0; k < 2; ++k) {
            float4 a = r4[k]; r[4*k]=a.x; r[4*k+1]=a.y; r[4*k+2]=a.z; r[4*k+3]=a.w;
            float4 b = v4[k]; v[4*k]=b.x; v[4*k+1]=b.y; v[4*k+2]=b.z; v[4*k+3]=b.w;
            float4 q = n4[k]; nv[4*k]=q.x; nv[4*k+1]=q.y; nv[4*k+2]=q.z; nv[4*k+3]=q.w;
        }
        int tm[ITEMS], tr[ITEMS];
        load_bool8(term,  base, mode, tm);
        load_bool8(trunc, base, mode, tr);
#pragma unroll
        for (int j = 0; j < ITEMS; ++j) {
            float nt = tm[j] ? 0.f : 1.f;
            float nd = (tm[j] | tr[j]) ? 0.f : 1.f;
            d[j] = r[j] + GAMMA_F * nt * nv[j] - v[j];
            c[j] = nd * GL;
        }
    } else {
#pragma unroll
        for (int j = 0; j < ITEMS; ++j) {
            long i = base + j;
            if (i < (long)n) {
                int tm = load_bool1(term, i, mode);
                int tr = load_bool1(trunc, i, mode);
                float nt = tm ? 0.f : 1.f;
                float nd = (tm | tr) ? 0.f : 1.f;
                v[j] = values[i];
                d[j] = rewards[i] + GAMMA_F * nt * next_values[i] - v[j];
                c[j] = nd * GL;
            } else { c[j] = 1.f; d[j] = 0.f; v[j] = 0.f; }
        }
    }
}

// per-thread within-block entry map (ea,eb) + block aggregate publication.
// Used IDENTICALLY (same FP ops, same order) by k1 and k3, so k3's recomputed
// (ea,eb) is bit-identical to what k1 used for the moment scalars — this is
// what lets us drop the 4 MB E2 round-trip entirely.
__device__ __forceinline__ void block_entry(
    const float* c, const float* d, int t, int lane, int w,
    float* wA, float* wB, float& ea, float& eb, float2* aggOut /*nullable*/)
{
    float a = 1.f, b = 0.f;
#pragma unroll
    for (int j = ITEMS - 1; j >= 0; --j) { b = fmaf(c[j], b, d[j]); a *= c[j]; }

    // wave suffix-inclusive scan via shuffles: H_l = F_l ∘ ... ∘ F_63
#pragma unroll
    for (int dd = 1; dd < 64; dd <<= 1) {
        float ra = __shfl_down(a, dd, 64);
        float rb = __shfl_down(b, dd, 64);
        if (lane + dd < 64) { b = fmaf(a, rb, b); a *= ra; }
    }
    if (lane == 0) { wA[w] = a; wB[w] = b; }   // wave aggregate
    // within-wave exclusive entry E = H_{l+1} (identity at lane 63)
    ea = __shfl_down(a, 1, 64);
    eb = __shfl_down(b, 1, 64);
    if (lane == 63) { ea = 1.f; eb = 0.f; }
    __syncthreads();
    for (int ww = w + 1; ww < 4; ++ww) compose(ea, eb, wA[ww], wB[ww]);
    if (aggOut && t == 0) {
        float Aa = wA[0], Ab = wB[0];
        for (int ww = 1; ww < 4; ++ww) compose(Aa, Ab, wA[ww], wB[ww]);
        *aggOut = make_float2(Aa, Ab);
    }
}

// ---------------- K1: block aggregates + moment scalars (28 KB written) -----
// 2-kernel structure is FINAL for this problem. In-kernel grid barriers were
// tried exhaustively and all lose to the ~5-10 µs dispatch boundary:
//   cg::grid.sync() (1024 same-addr RMW)          -> 210 µs
//   per-block flags + 262K acquire-pollers        -> 405 µs
//   hierarchical flags + agent fences             ->  73 µs
//     (buffer_wbl2 x1024 arrivals + buffer_inv in every wave, which also
//      evicts the L2-resident inputs; plus cross-barrier VGPR spills)
// The dispatch boundary IS the cheap grid barrier on MI355X.
__global__ __launch_bounds__(BLOCK) void k1_agg(
    const float* __restrict__ rewards, const float* __restrict__ values,
    const float* __restrict__ next_values, const void* __restrict__ term,
    const void* __restrict__ trunc, float2* __restrict__ blockAgg,
    float4* __restrict__ bs4, float* __restrict__ bs1, int n)
{
    __shared__ int flg[2];
    __shared__ float wA[4], wB[4];
    __shared__ float red[4][5];

    const int t = threadIdx.x;
    const int lane = t & 63, w = t >> 6;
    const int bid = blockIdx.x;
    const int mode = detect_mode(term, n, flg);
    const long base = (long)bid * CHUNK + (long)t * ITEMS;

    float c[ITEMS], d[ITEMS], v[ITEMS];
    compute_cd(rewards, values, next_values, term, trunc, mode, base, n, c, d, v);

    float ea, eb;
    block_entry(c, d, t, lane, w, wA, wB, ea, eb, &blockAgg[bid]);

    // symbolic replay: adv_j = p*x_b + q ; accumulate 5 moment scalars
    float p = ea, q = eb;
    float sP = 0.f, sQ = 0.f, sP2 = 0.f, sPQ = 0.f, sQ2 = 0.f;
#pragma unroll
    for (int j = ITEMS - 1; j >= 0; --j) {
        p = c[j] * p;
        q = fmaf(c[j], q, d[j]);
        if (base + j < (long)n) {
            sP += p; sQ += q; sP2 += p*p; sPQ += p*q; sQ2 += q*q;
        }
    }
#pragma unroll
    for (int dd = 32; dd > 0; dd >>= 1) {
        sP  += __shfl_down(sP,  dd, 64);
        sQ  += __shfl_down(sQ,  dd, 64);
        sP2 += __shfl_down(sP2, dd, 64);
        sPQ += __shfl_down(sPQ, dd, 64);
        sQ2 += __shfl_down(sQ2, dd, 64);
    }
    if (lane == 0) { red[w][0]=sP; red[w][1]=sQ; red[w][2]=sP2; red[w][3]=sPQ; red[w][4]=sQ2; }
    __syncthreads();
    if (t == 0) {
        float m0=0,m1=0,m2=0,m3=0,m4=0;
        for (int ww = 0; ww < 4; ++ww) { m0+=red[ww][0]; m1+=red[ww][1]; m2+=red[ww][2]; m3+=red[ww][3]; m4+=red[ww][4]; }
        bs4[bid] = make_float4(m0, m1, m2, m3);
        bs1[bid] = m4;
    }
}

// ---------------- K3: finalize; every block redundantly derives S[bid]+stats -
// Re-reads the inputs (L3-resident after k1: 44 MB < 256 MB Infinity Cache)
// and recomputes c,d,v AND the entry map (ea,eb) — no E2 traffic at all.
__global__ __launch_bounds__(BLOCK) void k3_final(
    const float* __restrict__ rewards, const float* __restrict__ values,
    const float* __restrict__ next_values, const void* __restrict__ term,
    const void* __restrict__ trunc, const float* __restrict__ lp,
    const float* __restrict__ olp, const float2* __restrict__ blockAgg,
    const float4* __restrict__ bs4, const float* __restrict__ bs1,
    float* __restrict__ out, int n, int nb)
{
    __shared__ int flg[2];
    __shared__ float wA[4], wB[4];
    __shared__ float sA[BLOCK], sB[BLOCK];
    __shared__ float sS[MAXNB];
    __shared__ double dS[BLOCK], dS2[BLOCK];
    __shared__ float statMean, statInv;

    const int t = threadIdx.x;
    const int lane = t & 63, w = t >> 6;
    const int bid = blockIdx.x;
    const int mode = detect_mode(term, n, flg);
    const long base = (long)bid * CHUNK + (long)t * ITEMS;

    float c[ITEMS], d[ITEMS], v[ITEMS];
    compute_cd(rewards, values, next_values, term, trunc, mode, base, n, c, d, v);

    // recompute per-thread entry map (bit-identical to k1's)
    float ea, eb;
    block_entry(c, d, t, lane, w, wA, wB, ea, eb, nullptr);
    __syncthreads();   // wA/wB done before sA/sB phase reuses sync slots

    // ---- redundant per-block suffix scan of nb aggregates + stats ----
    float la[4], lb[4];
#pragma unroll
    for (int j = 0; j < 4; ++j) {
        int i = 4 * t + j;
        if (i < nb) { float2 f = blockAgg[i]; la[j] = f.x; lb[j] = f.y; }
        else        { la[j] = 1.f; lb[j] = 0.f; }
    }
    float a = 1.f, b = 0.f;
#pragma unroll
    for (int j = 3; j >= 0; --j) { b = fmaf(la[j], b, lb[j]); a *= la[j]; }
    sA[t] = a; sB[t] = b;
    __syncthreads();
    for (int dd = 1; dd < BLOCK; dd <<= 1) {
        float ra = 1.f, rb = 0.f;
        if (t + dd < BLOCK) { ra = sA[t + dd]; rb = sB[t + dd]; }
        __syncthreads();
        b = fmaf(a, rb, b);
        a *= ra;
        sA[t] = a; sB[t] = b;
        __syncthreads();
    }
    {
        float x = (t + 1 < BLOCK) ? sB[t + 1] : 0.f;   // suffix entering block 4t+3
        double ds = 0.0, ds2 = 0.0;
#pragma unroll
        for (int j = 3; j >= 0; --j) {
            int i = 4 * t + j;
            if (i < nb) {
                sS[i] = x;
                float4 s4 = bs4[i];
                double xd = (double)x;
                ds  += (double)s4.x * xd + (double)s4.y;
                ds2 += (double)s4.z * xd * xd + 2.0 * (double)s4.w * xd + (double)bs1[i];
            }
            x = fmaf(la[j], x, lb[j]);
        }
        dS[t] = ds; dS2[t] = ds2;
    }
    __syncthreads();
    for (int dd = BLOCK / 2; dd > 0; dd >>= 1) {
        if (t < dd) { dS[t] += dS[t + dd]; dS2[t] += dS2[t + dd]; }
        __syncthreads();
    }
    if (t == 0) {
        double sum = dS[0], sumsq = dS2[0];
        double mean = sum / (double)n;
        double var = (sumsq - sum * sum / (double)n) / (double)(n - 1);
        if (var < 0.0) var = 0.0;
        statMean = (float)mean;
        statInv  = 1.0f / ((float)sqrt(var) + 1e-9f);
    }
    __syncthreads();

    // ---- replay + finalize ----
    float xx = fmaf(ea, sS[bid], eb);
    float adv[ITEMS];
#pragma unroll
    for (int j = ITEMS - 1; j >= 0; --j) {
        xx = fmaf(c[j], xx, d[j]);
        adv[j] = xx;
    }
    const float mean = statMean;
    const float inv  = statInv;
    if (base + ITEMS <= n) {
        float l[ITEMS], o[ITEMS];
        const float4* l4 = (const float4*)(lp + base);
        const float4* o4 = (const float4*)(olp + base);
#pragma unroll
        for (int k = 0; k < 2; ++k) {
            float4 q = l4[k]; l[4*k]=q.x; l[4*k+1]=q.y; l[4*k+2]=q.z; l[4*k+3]=q.w;
            float4 ww = o4[k]; o[4*k]=ww.x; o[4*k+1]=ww.y; o[4*k+2]=ww.z; o[4*k+3]=ww.w;
        }
        float buf[3 * ITEMS];
#pragma unroll
        for (int j = 0; j < ITEMS; ++j) {
            float an = (adv[j] - mean) * inv;
            float ratio = expf(l[j] - o[j]);
            float cl = fminf(fmaxf(ratio, 0.8f), 1.2f);
            buf[3*j]     = an;
            buf[3*j + 1] = adv[j] + v[j];
            buf[3*j + 2] = -fminf(ratio * an, cl * an);
        }
        float4* dst = (float4*)(out + 3 * base);   // 3*base % 4 == 0 → 16B aligned
#pragma unroll
        for (int k = 0; k < 6; ++k)
            dst[k] = make_float4(buf[4*k], buf[4*k+1], buf[4*k+2], buf[4*k+3]);
    } else {
        for (int j = 0; j < ITEMS; ++j) {
            long i = base + j;
            if (i < (long)n) {
                float an = (adv[j] - mean) * inv;
                float ratio = expf(lp[i] - olp[i]);
                float cl = fminf(fmaxf(ratio, 0.8f), 1.2f);
                out[3*i]     = an;
                out[3*i + 1] = adv[j] + v[j];
                out[3*i + 2] = -fminf(ratio * an, cl * an);
            }
        }
    }
}

extern "C" void kernel_launch(void* const* d_in, const int* in_sizes, int n_in,
                              void* d_out, int out_size, void* d_ws, size_t ws_size,
                              hipStream_t stream) {
    const float* rewards     = (const float*)d_in[0];
    const float* values      = (const float*)d_in[1];
    const float* next_values = (const float*)d_in[2];
    const float* lp          = (const float*)d_in[3];
    const float* olp         = (const float*)d_in[4];
    const void*  term        = d_in[5];
    const void*  trunc       = d_in[6];
    float* out = (float*)d_out;
    int n = in_sizes[0];
    int nb = (n + CHUNK - 1) / CHUNK;   // 1024 for N=2^21; must be <= MAXNB

    char* ws = (char*)d_ws;
    float2* blockAgg = (float2*)ws;                                   // 8 KB
    float4* bs4      = (float4*)(ws + MAXNB * 8);                     // 16 KB
    float*  bs1      = (float*) (ws + MAXNB * 8 + MAXNB * 16);        // 4 KB

    k1_agg <<<nb, BLOCK, 0, stream>>>(rewards, values, next_values, term, trunc,
                                      blockAgg, bs4, bs1, n);
    k3_final<<<nb, BLOCK, 0, stream>>>(rewards, values, next_values, term, trunc,
                                       lp, olp, blockAgg, bs4, bs1, out, n, nb);
}